// Round 15
// baseline (106.329 us; speedup 1.0000x reference)
//
#include <hip/hip_runtime.h>
#include <cstdint>
#include <cstddef>

#define BATCH 32
#define CLEN  1024
#define QLEN  128
#define HID   256

typedef __attribute__((ext_vector_type(8))) short bf16x8;
typedef __attribute__((ext_vector_type(4))) float f32x4;

#define MFMA(a, b, c) __builtin_amdgcn_mfma_f32_16x16x32_bf16((a), (b), (c), 0, 0, 0)

__device__ __forceinline__ ushort f2b(float f) {
    union { float f; uint u; } v; v.f = f;
    uint r = (v.u + 0x7fffu + ((v.u >> 16) & 1u)) >> 16;
    return (ushort)r;
}
__device__ __forceinline__ float b2f(ushort u) {
    union { uint u; float f; } v; v.u = ((uint)u) << 16;
    return v.f;
}

// ================= prep (R13 verbatim) =================
__global__ __launch_bounds__(256) void prep_kernel(
    const float* __restrict__ context, const float* __restrict__ query,
    const float* __restrict__ cw, const float* __restrict__ qw,
    const float* __restrict__ cqw,
    ushort* __restrict__ ctxB, ushort* __restrict__ ctxT,
    ushort* __restrict__ qmB, ushort* __restrict__ qT,
    float* __restrict__ cdot, float* __restrict__ qdot)
{
    __shared__ ushort lds[64][258];
    int bid = blockIdx.x;
    int t = threadIdx.x;
    int r = t >> 2, qd = t & 3;
    if (bid < 512) {
        int b = bid >> 4, c0 = (bid & 15) * 64;
        const float* src = context + ((size_t)(b * CLEN + c0 + r)) * HID;
        ushort* cbr = ctxB + ((size_t)(b * CLEN + c0 + r)) * HID;
        float dot = 0.f;
        #pragma unroll
        for (int j = 0; j < 16; j++) {
            int h = j * 16 + qd * 4;
            float4 v = *reinterpret_cast<const float4*>(src + h);
            float4 w = *reinterpret_cast<const float4*>(cw + h);
            dot += v.x * w.x + v.y * w.y + v.z * w.z + v.w * w.w;
            uint p0 = (uint)f2b(v.x) | ((uint)f2b(v.y) << 16);
            uint p1 = (uint)f2b(v.z) | ((uint)f2b(v.w) << 16);
            *reinterpret_cast<uint*>(&lds[r][h])     = p0;
            *reinterpret_cast<uint*>(&lds[r][h + 2]) = p1;
            uint2 pk; pk.x = p0; pk.y = p1;
            *reinterpret_cast<uint2*>(cbr + h) = pk;
        }
        dot += __shfl_xor(dot, 1);
        dot += __shfl_xor(dot, 2);
        if (qd == 0) cdot[b * CLEN + c0 + r] = dot;
        __syncthreads();
        ushort* dst = ctxT + ((size_t)(b * HID + t)) * CLEN + c0;
        #pragma unroll
        for (int j = 0; j < 8; j++) {
            uint4 w;
            w.x = (uint)lds[j*8+0][t] | ((uint)lds[j*8+1][t] << 16);
            w.y = (uint)lds[j*8+2][t] | ((uint)lds[j*8+3][t] << 16);
            w.z = (uint)lds[j*8+4][t] | ((uint)lds[j*8+5][t] << 16);
            w.w = (uint)lds[j*8+6][t] | ((uint)lds[j*8+7][t] << 16);
            *reinterpret_cast<uint4*>(dst + j * 8) = w;
        }
    } else {
        int bb = bid - 512;
        int b = bb >> 1, q0 = (bb & 1) * 64;
        const float* src = query + ((size_t)(b * QLEN + q0 + r)) * HID;
        ushort* qmr = qmB + ((size_t)(b * QLEN + q0 + r)) * HID;
        float dot = 0.f;
        #pragma unroll
        for (int j = 0; j < 16; j++) {
            int h = j * 16 + qd * 4;
            float4 v   = *reinterpret_cast<const float4*>(src + h);
            float4 w   = *reinterpret_cast<const float4*>(qw + h);
            float4 wc4 = *reinterpret_cast<const float4*>(cqw + h);
            dot += v.x * w.x + v.y * w.y + v.z * w.z + v.w * w.w;
            uint p0 = (uint)f2b(v.x) | ((uint)f2b(v.y) << 16);
            uint p1 = (uint)f2b(v.z) | ((uint)f2b(v.w) << 16);
            *reinterpret_cast<uint*>(&lds[r][h])     = p0;
            *reinterpret_cast<uint*>(&lds[r][h + 2]) = p1;
            uint2 mc;
            mc.x = (uint)f2b(v.x * wc4.x) | ((uint)f2b(v.y * wc4.y) << 16);
            mc.y = (uint)f2b(v.z * wc4.z) | ((uint)f2b(v.w * wc4.w) << 16);
            *reinterpret_cast<uint2*>(qmr + h) = mc;
        }
        dot += __shfl_xor(dot, 1);
        dot += __shfl_xor(dot, 2);
        if (qd == 0) qdot[b * QLEN + q0 + r] = dot;
        __syncthreads();
        ushort* dst = qT + ((size_t)(b * HID + t)) * QLEN + q0;
        #pragma unroll
        for (int j = 0; j < 8; j++) {
            uint4 w;
            w.x = (uint)lds[j*8+0][t] | ((uint)lds[j*8+1][t] << 16);
            w.y = (uint)lds[j*8+2][t] | ((uint)lds[j*8+3][t] << 16);
            w.z = (uint)lds[j*8+4][t] | ((uint)lds[j*8+5][t] << 16);
            w.w = (uint)lds[j*8+6][t] | ((uint)lds[j*8+7][t] << 16);
            *reinterpret_cast<uint4*>(dst + j * 8) = w;
        }
    }
}

// ====== s_kernel (R13 verbatim) ======
__global__ __launch_bounds__(256) void s_kernel(
    const ushort* __restrict__ ctxB, const ushort* __restrict__ qmB,
    const float* __restrict__ cdot, const float* __restrict__ qdot,
    const float* __restrict__ bias,
    ushort* __restrict__ S, ushort* __restrict__ P2T,
    float* __restrict__ psum)
{
    __shared__ float ldsS[64][132];
    __shared__ float ldsM[64], ldsR[64];
    __shared__ float ldsP[2][128];
    int ct = blockIdx.x, b = blockIdx.y;
    int c0 = ct * 64;
    int t = threadIdx.x;
    int w = t >> 6, L = t & 63, g = L >> 4, ln = L & 15;
    int wr = w >> 1, wc = w & 1;

    f32x4 acc[2][4];
    #pragma unroll
    for (int mi = 0; mi < 2; mi++)
        #pragma unroll
        for (int ni = 0; ni < 4; ni++) acc[mi][ni] = (f32x4){0.f, 0.f, 0.f, 0.f};

    const ushort* aBase = ctxB + ((size_t)(b * CLEN + c0 + wr * 32)) * HID;
    const ushort* qBb   = qmB + ((size_t)(b * QLEN + wc * 64)) * HID;

    #pragma unroll 2
    for (int kk = 0; kk < 8; kk++) {
        int k = kk * 32 + g * 8;
        bf16x8 a[2], bq[4];
        #pragma unroll
        for (int mi = 0; mi < 2; mi++)
            a[mi] = *reinterpret_cast<const bf16x8*>(aBase + (size_t)(mi * 16 + ln) * HID + k);
        #pragma unroll
        for (int ni = 0; ni < 4; ni++)
            bq[ni] = *reinterpret_cast<const bf16x8*>(qBb + (size_t)(ni * 16 + ln) * HID + k);
        #pragma unroll
        for (int mi = 0; mi < 2; mi++)
            #pragma unroll
            for (int ni = 0; ni < 4; ni++)
                acc[mi][ni] = MFMA(a[mi], bq[ni], acc[mi][ni]);
    }

    float bv = bias[0];
    float qdv[4];
    #pragma unroll
    for (int ni = 0; ni < 4; ni++) qdv[ni] = qdot[b * QLEN + wc * 64 + ni * 16 + ln];
    #pragma unroll
    for (int mi = 0; mi < 2; mi++)
        #pragma unroll
        for (int r = 0; r < 4; r++) {
            int row = wr * 32 + mi * 16 + g * 4 + r;
            float cd = cdot[b * CLEN + c0 + row] + bv;
            #pragma unroll
            for (int ni = 0; ni < 4; ni++)
                ldsS[row][wc * 64 + ni * 16 + ln] = acc[mi][ni][r] + cd + qdv[ni];
        }
    __syncthreads();
    {
        int row = t >> 2, qs = (t & 3) * 32;
        float4 vr[8];
        float mx = -1e30f;
        #pragma unroll
        for (int j = 0; j < 8; j++) {
            vr[j] = *reinterpret_cast<const float4*>(&ldsS[row][qs + j * 4]);
            mx = fmaxf(mx, fmaxf(fmaxf(vr[j].x, vr[j].y), fmaxf(vr[j].z, vr[j].w)));
        }
        mx = fmaxf(mx, __shfl_xor(mx, 1));
        mx = fmaxf(mx, __shfl_xor(mx, 2));
        float s = 0.f;
        #pragma unroll
        for (int j = 0; j < 8; j++)
            s += __expf(vr[j].x - mx) + __expf(vr[j].y - mx) +
                 __expf(vr[j].z - mx) + __expf(vr[j].w - mx);
        s += __shfl_xor(s, 1);
        s += __shfl_xor(s, 2);
        if ((t & 3) == 0) { ldsM[row] = mx; ldsR[row] = 1.0f / s; }
    }
    __syncthreads();
    {
        const size_t Sbase = ((size_t)b * CLEN + c0) * QLEN;
        #pragma unroll
        for (int i = 0; i < 8; i++) {
            int flat = t + 256 * i;
            int q4 = flat & 31, c = flat >> 5;
            float4 v = *reinterpret_cast<const float4*>(&ldsS[c][q4 * 4]);
            uint2 pk;
            pk.x = (uint)f2b(v.x) | ((uint)f2b(v.y) << 16);
            pk.y = (uint)f2b(v.z) | ((uint)f2b(v.w) << 16);
            *reinterpret_cast<uint2*>(&S[Sbase + (size_t)c * QLEN + q4 * 4]) = pk;
        }
    }
    {
        int q = t >> 1, half = t & 1;
        ushort* dst = P2T + ((size_t)b * QLEN + q) * CLEN + c0 + half * 32;
        #pragma unroll
        for (int jo = 0; jo < 4; jo++) {
            uint pk[4];
            #pragma unroll
            for (int l = 0; l < 4; l++) {
                int c0l = half * 32 + jo * 8 + l * 2;
                float p0 = __expf(ldsS[c0l][q]     - ldsM[c0l])     * ldsR[c0l];
                float p1 = __expf(ldsS[c0l + 1][q] - ldsM[c0l + 1]) * ldsR[c0l + 1];
                pk[l] = (uint)f2b(p0) | ((uint)f2b(p1) << 16);
            }
            uint4 wv; wv.x = pk[0]; wv.y = pk[1]; wv.z = pk[2]; wv.w = pk[3];
            *reinterpret_cast<uint4*>(dst + jo * 8) = wv;
        }
    }
    {
        int q = t & 127, hf = t >> 7;
        float s = 0.f;
        #pragma unroll
        for (int cc = 0; cc < 32; cc++)
            s += __expf(b2f(f2b(ldsS[hf * 32 + cc][q])));
        ldsP[hf][q] = s;
    }
    __syncthreads();
    if (t < 128)
        psum[((size_t)b * 16 + ct) * QLEN + t] = ldsP[0][t] + ldsP[1][t];
}

// ====== t_kernel: single-K (1024), SR from psum in-block, writes Tt bf16 ======
// grid (4 htile64, 32 b); waves 2x2, wave 32h x 64q, acc 2x4
__global__ __launch_bounds__(256) void t_kernel(
    const ushort* __restrict__ ctxT, const ushort* __restrict__ P2T,
    const float* __restrict__ psum, ushort* __restrict__ Tt)
{
    __shared__ float SR[128];
    int x = blockIdx.x, b = blockIdx.y;
    int h0 = x * 64;
    int t = threadIdx.x;
    if (t < 128) {
        float s = 0.f;
        #pragma unroll
        for (int j = 0; j < 16; j++)
            s += psum[((size_t)b * 16 + j) * QLEN + t];
        SR[t] = 1.0f / s;
    }
    __syncthreads();
    int w = t >> 6, L = t & 63, g = L >> 4, ln = L & 15;
    int wr = w >> 1, wc = w & 1;

    f32x4 acc[2][4];
    #pragma unroll
    for (int mi = 0; mi < 2; mi++)
        #pragma unroll
        for (int ni = 0; ni < 4; ni++) acc[mi][ni] = (f32x4){0.f, 0.f, 0.f, 0.f};

    const ushort* aB = ctxT + ((size_t)(b * HID + h0 + wr * 32)) * CLEN;
    const ushort* bB = P2T + ((size_t)(b * QLEN + wc * 64)) * CLEN;

    #pragma unroll 2
    for (int kk = 0; kk < 32; kk++) {
        int k = kk * 32 + g * 8;
        bf16x8 a[2], bq[4];
        #pragma unroll
        for (int mi = 0; mi < 2; mi++)
            a[mi] = *reinterpret_cast<const bf16x8*>(aB + (size_t)(mi * 16 + ln) * CLEN + k);
        #pragma unroll
        for (int ni = 0; ni < 4; ni++)
            bq[ni] = *reinterpret_cast<const bf16x8*>(bB + (size_t)(ni * 16 + ln) * CLEN + k);
        #pragma unroll
        for (int mi = 0; mi < 2; mi++)
            #pragma unroll
            for (int ni = 0; ni < 4; ni++)
                acc[mi][ni] = MFMA(a[mi], bq[ni], acc[mi][ni]);
    }
    #pragma unroll
    for (int mi = 0; mi < 2; mi++)
        #pragma unroll
        for (int ni = 0; ni < 4; ni++) {
            int q = wc * 64 + ni * 16 + ln;
            float cr = SR[q];
            #pragma unroll
            for (int r = 0; r < 4; r++) {
                int h = h0 + wr * 32 + mi * 16 + g * 4 + r;
                Tt[((size_t)b * HID + h) * QLEN + q] = f2b(acc[mi][ni][r] * cr);
            }
        }
}

// ====== ab_out (R13 verbatim, 64c x 128h) ======
__global__ __launch_bounds__(256) void ab_out_kernel(
    const ushort* __restrict__ S, const ushort* __restrict__ qT,
    const ushort* __restrict__ Tt, const ushort* __restrict__ ctxB,
    float* __restrict__ out)
{
    __shared__ float ldsA[64][68];
    __shared__ float ldsB[64][68];
    int x = blockIdx.x, b = blockIdx.y;
    int c0 = (x & 15) * 64, h0 = (x >> 4) * 128;
    int t = threadIdx.x;
    int wv = t >> 6, L = t & 63, g = L >> 4, ln = L & 15;

    f32x4 accA[4][2], accB[4][2];
    #pragma unroll
    for (int mi = 0; mi < 4; mi++)
        #pragma unroll
        for (int ni = 0; ni < 2; ni++) {
            accA[mi][ni] = (f32x4){0.f, 0.f, 0.f, 0.f};
            accB[mi][ni] = (f32x4){0.f, 0.f, 0.f, 0.f};
        }

    const ushort* Srow = S + ((size_t)(b * CLEN + c0)) * QLEN;
    const ushort* qTb  = qT + ((size_t)(b * HID + h0 + wv * 32)) * QLEN;
    const ushort* TtB  = Tt + ((size_t)(b * HID + h0 + wv * 32)) * QLEN;

    #pragma unroll
    for (int kk = 0; kk < 4; kk++) {
        int k = kk * 32 + g * 8;
        bf16x8 sa[4], pa[4], bq[2], bt[2];
        #pragma unroll
        for (int mi = 0; mi < 4; mi++) {
            sa[mi] = *reinterpret_cast<const bf16x8*>(Srow + (size_t)(mi * 16 + ln) * QLEN + k);
            bf16x8 pv;
            #pragma unroll
            for (int i = 0; i < 8; i++)
                pv[i] = (short)f2b(__expf(b2f((ushort)sa[mi][i])));
            pa[mi] = pv;
        }
        #pragma unroll
        for (int ni = 0; ni < 2; ni++) {
            bq[ni] = *reinterpret_cast<const bf16x8*>(qTb + (size_t)(ni * 16 + ln) * QLEN + k);
            bt[ni] = *reinterpret_cast<const bf16x8*>(TtB + (size_t)(ni * 16 + ln) * QLEN + k);
        }
        #pragma unroll
        for (int mi = 0; mi < 4; mi++)
            #pragma unroll
            for (int ni = 0; ni < 2; ni++) {
                accA[mi][ni] = MFMA(sa[mi], bq[ni], accA[mi][ni]);
                accB[mi][ni] = MFMA(pa[mi], bt[ni], accB[mi][ni]);
            }
    }

    #pragma unroll
    for (int hh = 0; hh < 2; hh++) {
        if ((wv >> 1) == hh) {
            int hc = wv & 1;
            #pragma unroll
            for (int mi = 0; mi < 4; mi++)
                #pragma unroll
                for (int ni = 0; ni < 2; ni++)
                    #pragma unroll
                    for (int r = 0; r < 4; r++) {
                        ldsA[mi * 16 + g * 4 + r][hc * 32 + ni * 16 + ln] = accA[mi][ni][r];
                        ldsB[mi * 16 + g * 4 + r][hc * 32 + ni * 16 + ln] = accB[mi][ni][r];
                    }
        }
        __syncthreads();
        #pragma unroll
        for (int i = 0; i < 2; i++) {
            int flat = t + 256 * i;
            int h8 = flat & 7, c = flat >> 3;
            bf16x8 cb = *reinterpret_cast<const bf16x8*>(
                ctxB + ((size_t)(b * CLEN + c0 + c)) * HID + h0 + hh * 64 + h8 * 8);
            float cf[8];
            #pragma unroll
            for (int j = 0; j < 8; j++) cf[j] = b2f((ushort)cb[j]);
            float4 a0 = *reinterpret_cast<const float4*>(&ldsA[c][h8 * 8]);
            float4 a1 = *reinterpret_cast<const float4*>(&ldsA[c][h8 * 8 + 4]);
            float4 b0 = *reinterpret_cast<const float4*>(&ldsB[c][h8 * 8]);
            float4 b1 = *reinterpret_cast<const float4*>(&ldsB[c][h8 * 8 + 4]);
            size_t o = ((size_t)(b * CLEN + c0 + c)) * 1024 + h0 + hh * 64 + h8 * 8;
            *reinterpret_cast<float4*>(&out[o])     = make_float4(cf[0], cf[1], cf[2], cf[3]);
            *reinterpret_cast<float4*>(&out[o + 4]) = make_float4(cf[4], cf[5], cf[6], cf[7]);
            *reinterpret_cast<float4*>(&out[o + 256]) = a0;
            *reinterpret_cast<float4*>(&out[o + 260]) = a1;
            *reinterpret_cast<float4*>(&out[o + 512]) =
                make_float4(cf[0] * a0.x, cf[1] * a0.y, cf[2] * a0.z, cf[3] * a0.w);
            *reinterpret_cast<float4*>(&out[o + 516]) =
                make_float4(cf[4] * a1.x, cf[5] * a1.y, cf[6] * a1.z, cf[7] * a1.w);
            *reinterpret_cast<float4*>(&out[o + 768]) =
                make_float4(cf[0] * b0.x, cf[1] * b0.y, cf[2] * b0.z, cf[3] * b0.w);
            *reinterpret_cast<float4*>(&out[o + 772]) =
                make_float4(cf[4] * b1.x, cf[5] * b1.y, cf[6] * b1.z, cf[7] * b1.w);
        }
        __syncthreads();
    }
}

extern "C" void kernel_launch(void* const* d_in, const int* in_sizes, int n_in,
                              void* d_out, int out_size, void* d_ws, size_t ws_size,
                              hipStream_t stream)
{
    (void)in_sizes; (void)n_in; (void)out_size; (void)ws_size;
    const float* context   = (const float*)d_in[0];
    const float* query     = (const float*)d_in[1];
    const float* c_weight  = (const float*)d_in[4];
    const float* q_weight  = (const float*)d_in[5];
    const float* cq_weight = (const float*)d_in[6];
    const float* bias      = (const float*)d_in[7];
    float* out = (float*)d_out;
    char* wsb  = (char*)d_ws;

    ushort* ctxB = (ushort*)(wsb);                       // 16,777,216 B
    ushort* ctxT = (ushort*)(wsb + 16777216);            // 16,777,216 B
    ushort* qmB  = (ushort*)(wsb + 33554432);            //  2,097,152 B
    ushort* qT   = (ushort*)(wsb + 35651584);            //  2,097,152 B
    ushort* S    = (ushort*)(wsb + 37748736);            //  8,388,608 B
    ushort* P2T  = (ushort*)(wsb + 46137344);            //  8,388,608 B
    ushort* Tt   = (ushort*)(wsb + 54525952);            //  2,097,152 B
    float*  cdot = (float*)(wsb + 56623104);             //    131,072 B
    float*  qdot = cdot + 32768;                         //     16,384 B
    float*  psum = qdot + 4096;                          //    262,144 B

    prep_kernel<<<576, 256, 0, stream>>>(context, query, c_weight, q_weight,
                                         cq_weight, ctxB, ctxT, qmB, qT,
                                         cdot, qdot);
    s_kernel<<<dim3(16, 32), 256, 0, stream>>>(ctxB, qmB, cdot, qdot, bias,
                                               S, P2T, psum);
    t_kernel<<<dim3(4, 32), 256, 0, stream>>>(ctxT, P2T, psum, Tt);
    ab_out_kernel<<<dim3(32, 32), 256, 0, stream>>>(S, qT, Tt, ctxB, out);
}

// Round 16
// 99.465 us; speedup vs baseline: 1.0690x; 1.0690x over previous
//
#include <hip/hip_runtime.h>
#include <cstdint>
#include <cstddef>

#define BATCH 32
#define CLEN  1024
#define QLEN  128
#define HID   256

typedef __attribute__((ext_vector_type(8))) short bf16x8;
typedef __attribute__((ext_vector_type(4))) float f32x4;

#define MFMA(a, b, c) __builtin_amdgcn_mfma_f32_16x16x32_bf16((a), (b), (c), 0, 0, 0)

__device__ __forceinline__ ushort f2b(float f) {
    union { float f; uint u; } v; v.f = f;
    uint r = (v.u + 0x7fffu + ((v.u >> 16) & 1u)) >> 16;
    return (ushort)r;
}
__device__ __forceinline__ float b2f(ushort u) {
    union { uint u; float f; } v; v.u = ((uint)u) << 16;
    return v.f;
}

// ================= prep =================
__global__ __launch_bounds__(256) void prep_kernel(
    const float* __restrict__ context, const float* __restrict__ query,
    const float* __restrict__ cw, const float* __restrict__ qw,
    const float* __restrict__ cqw,
    ushort* __restrict__ ctxB, ushort* __restrict__ ctxT,
    ushort* __restrict__ qmB, ushort* __restrict__ qT,
    float* __restrict__ cdot, float* __restrict__ qdot)
{
    __shared__ ushort lds[64][258];
    int bid = blockIdx.x;
    int t = threadIdx.x;
    int r = t >> 2, qd = t & 3;
    if (bid < 512) {
        int b = bid >> 4, c0 = (bid & 15) * 64;
        const float* src = context + ((size_t)(b * CLEN + c0 + r)) * HID;
        ushort* cbr = ctxB + ((size_t)(b * CLEN + c0 + r)) * HID;
        float dot = 0.f;
        #pragma unroll
        for (int j = 0; j < 16; j++) {
            int h = j * 16 + qd * 4;
            float4 v = *reinterpret_cast<const float4*>(src + h);
            float4 w = *reinterpret_cast<const float4*>(cw + h);
            dot += v.x * w.x + v.y * w.y + v.z * w.z + v.w * w.w;
            uint p0 = (uint)f2b(v.x) | ((uint)f2b(v.y) << 16);
            uint p1 = (uint)f2b(v.z) | ((uint)f2b(v.w) << 16);
            *reinterpret_cast<uint*>(&lds[r][h])     = p0;
            *reinterpret_cast<uint*>(&lds[r][h + 2]) = p1;
            uint2 pk; pk.x = p0; pk.y = p1;
            *reinterpret_cast<uint2*>(cbr + h) = pk;
        }
        dot += __shfl_xor(dot, 1);
        dot += __shfl_xor(dot, 2);
        if (qd == 0) cdot[b * CLEN + c0 + r] = dot;
        __syncthreads();
        ushort* dst = ctxT + ((size_t)(b * HID + t)) * CLEN + c0;
        #pragma unroll
        for (int j = 0; j < 8; j++) {
            uint4 w;
            w.x = (uint)lds[j*8+0][t] | ((uint)lds[j*8+1][t] << 16);
            w.y = (uint)lds[j*8+2][t] | ((uint)lds[j*8+3][t] << 16);
            w.z = (uint)lds[j*8+4][t] | ((uint)lds[j*8+5][t] << 16);
            w.w = (uint)lds[j*8+6][t] | ((uint)lds[j*8+7][t] << 16);
            *reinterpret_cast<uint4*>(dst + j * 8) = w;
        }
    } else {
        int bb = bid - 512;
        int b = bb >> 1, q0 = (bb & 1) * 64;
        const float* src = query + ((size_t)(b * QLEN + q0 + r)) * HID;
        ushort* qmr = qmB + ((size_t)(b * QLEN + q0 + r)) * HID;
        float dot = 0.f;
        #pragma unroll
        for (int j = 0; j < 16; j++) {
            int h = j * 16 + qd * 4;
            float4 v   = *reinterpret_cast<const float4*>(src + h);
            float4 w   = *reinterpret_cast<const float4*>(qw + h);
            float4 wc4 = *reinterpret_cast<const float4*>(cqw + h);
            dot += v.x * w.x + v.y * w.y + v.z * w.z + v.w * w.w;
            uint p0 = (uint)f2b(v.x) | ((uint)f2b(v.y) << 16);
            uint p1 = (uint)f2b(v.z) | ((uint)f2b(v.w) << 16);
            *reinterpret_cast<uint*>(&lds[r][h])     = p0;
            *reinterpret_cast<uint*>(&lds[r][h + 2]) = p1;
            uint2 mc;
            mc.x = (uint)f2b(v.x * wc4.x) | ((uint)f2b(v.y * wc4.y) << 16);
            mc.y = (uint)f2b(v.z * wc4.z) | ((uint)f2b(v.w * wc4.w) << 16);
            *reinterpret_cast<uint2*>(qmr + h) = mc;
        }
        dot += __shfl_xor(dot, 1);
        dot += __shfl_xor(dot, 2);
        if (qd == 0) qdot[b * QLEN + q0 + r] = dot;
        __syncthreads();
        ushort* dst = qT + ((size_t)(b * HID + t)) * QLEN + q0;
        #pragma unroll
        for (int j = 0; j < 8; j++) {
            uint4 w;
            w.x = (uint)lds[j*8+0][t] | ((uint)lds[j*8+1][t] << 16);
            w.y = (uint)lds[j*8+2][t] | ((uint)lds[j*8+3][t] << 16);
            w.z = (uint)lds[j*8+4][t] | ((uint)lds[j*8+5][t] << 16);
            w.w = (uint)lds[j*8+6][t] | ((uint)lds[j*8+7][t] << 16);
            *reinterpret_cast<uint4*>(dst + j * 8) = w;
        }
    }
}

// ====== s_kernel ======
__global__ __launch_bounds__(256) void s_kernel(
    const ushort* __restrict__ ctxB, const ushort* __restrict__ qmB,
    const float* __restrict__ cdot, const float* __restrict__ qdot,
    const float* __restrict__ bias,
    ushort* __restrict__ S, ushort* __restrict__ P2T,
    float* __restrict__ psum)
{
    __shared__ float ldsS[64][132];
    __shared__ float ldsM[64], ldsR[64];
    __shared__ float ldsP[2][128];
    int ct = blockIdx.x, b = blockIdx.y;
    int c0 = ct * 64;
    int t = threadIdx.x;
    int w = t >> 6, L = t & 63, g = L >> 4, ln = L & 15;
    int wr = w >> 1, wc = w & 1;

    f32x4 acc[2][4];
    #pragma unroll
    for (int mi = 0; mi < 2; mi++)
        #pragma unroll
        for (int ni = 0; ni < 4; ni++) acc[mi][ni] = (f32x4){0.f, 0.f, 0.f, 0.f};

    const ushort* aBase = ctxB + ((size_t)(b * CLEN + c0 + wr * 32)) * HID;
    const ushort* qBb   = qmB + ((size_t)(b * QLEN + wc * 64)) * HID;

    #pragma unroll 2
    for (int kk = 0; kk < 8; kk++) {
        int k = kk * 32 + g * 8;
        bf16x8 a[2], bq[4];
        #pragma unroll
        for (int mi = 0; mi < 2; mi++)
            a[mi] = *reinterpret_cast<const bf16x8*>(aBase + (size_t)(mi * 16 + ln) * HID + k);
        #pragma unroll
        for (int ni = 0; ni < 4; ni++)
            bq[ni] = *reinterpret_cast<const bf16x8*>(qBb + (size_t)(ni * 16 + ln) * HID + k);
        #pragma unroll
        for (int mi = 0; mi < 2; mi++)
            #pragma unroll
            for (int ni = 0; ni < 4; ni++)
                acc[mi][ni] = MFMA(a[mi], bq[ni], acc[mi][ni]);
    }

    float bv = bias[0];
    float qdv[4];
    #pragma unroll
    for (int ni = 0; ni < 4; ni++) qdv[ni] = qdot[b * QLEN + wc * 64 + ni * 16 + ln];
    #pragma unroll
    for (int mi = 0; mi < 2; mi++)
        #pragma unroll
        for (int r = 0; r < 4; r++) {
            int row = wr * 32 + mi * 16 + g * 4 + r;
            float cd = cdot[b * CLEN + c0 + row] + bv;
            #pragma unroll
            for (int ni = 0; ni < 4; ni++)
                ldsS[row][wc * 64 + ni * 16 + ln] = acc[mi][ni][r] + cd + qdv[ni];
        }
    __syncthreads();
    {
        int row = t >> 2, qs = (t & 3) * 32;
        float4 vr[8];
        float mx = -1e30f;
        #pragma unroll
        for (int j = 0; j < 8; j++) {
            vr[j] = *reinterpret_cast<const float4*>(&ldsS[row][qs + j * 4]);
            mx = fmaxf(mx, fmaxf(fmaxf(vr[j].x, vr[j].y), fmaxf(vr[j].z, vr[j].w)));
        }
        mx = fmaxf(mx, __shfl_xor(mx, 1));
        mx = fmaxf(mx, __shfl_xor(mx, 2));
        float s = 0.f;
        #pragma unroll
        for (int j = 0; j < 8; j++)
            s += __expf(vr[j].x - mx) + __expf(vr[j].y - mx) +
                 __expf(vr[j].z - mx) + __expf(vr[j].w - mx);
        s += __shfl_xor(s, 1);
        s += __shfl_xor(s, 2);
        if ((t & 3) == 0) { ldsM[row] = mx; ldsR[row] = 1.0f / s; }
    }
    __syncthreads();
    {
        const size_t Sbase = ((size_t)b * CLEN + c0) * QLEN;
        #pragma unroll
        for (int i = 0; i < 8; i++) {
            int flat = t + 256 * i;
            int q4 = flat & 31, c = flat >> 5;
            float4 v = *reinterpret_cast<const float4*>(&ldsS[c][q4 * 4]);
            uint2 pk;
            pk.x = (uint)f2b(v.x) | ((uint)f2b(v.y) << 16);
            pk.y = (uint)f2b(v.z) | ((uint)f2b(v.w) << 16);
            *reinterpret_cast<uint2*>(&S[Sbase + (size_t)c * QLEN + q4 * 4]) = pk;
        }
    }
    {
        int q = t >> 1, half = t & 1;
        ushort* dst = P2T + ((size_t)b * QLEN + q) * CLEN + c0 + half * 32;
        #pragma unroll
        for (int jo = 0; jo < 4; jo++) {
            uint pk[4];
            #pragma unroll
            for (int l = 0; l < 4; l++) {
                int c0l = half * 32 + jo * 8 + l * 2;
                float p0 = __expf(ldsS[c0l][q]     - ldsM[c0l])     * ldsR[c0l];
                float p1 = __expf(ldsS[c0l + 1][q] - ldsM[c0l + 1]) * ldsR[c0l + 1];
                pk[l] = (uint)f2b(p0) | ((uint)f2b(p1) << 16);
            }
            uint4 wv; wv.x = pk[0]; wv.y = pk[1]; wv.z = pk[2]; wv.w = pk[3];
            *reinterpret_cast<uint4*>(dst + jo * 8) = wv;
        }
    }
    {
        int q = t & 127, hf = t >> 7;
        float s = 0.f;
        #pragma unroll
        for (int cc = 0; cc < 32; cc++)
            s += __expf(b2f(f2b(ldsS[hf * 32 + cc][q])));
        ldsP[hf][q] = s;
    }
    __syncthreads();
    if (t < 128)
        psum[((size_t)b * 16 + ct) * QLEN + t] = ldsP[0][t] + ldsP[1][t];
}

// ====== t_kernel: Tpart[ks][b][h][q], K-split 2 ======
__global__ __launch_bounds__(256) void t_kernel(
    const ushort* __restrict__ ctxT, const ushort* __restrict__ P2T,
    float* __restrict__ Tpart)
{
    int x = blockIdx.x, b = blockIdx.y;
    int h0 = (x >> 1) * 64, ks = x & 1;
    int t = threadIdx.x;
    int w = t >> 6, L = t & 63, g = L >> 4, ln = L & 15;
    int wr = w >> 1, wc = w & 1;

    f32x4 acc[2][4];
    #pragma unroll
    for (int mi = 0; mi < 2; mi++)
        #pragma unroll
        for (int ni = 0; ni < 4; ni++) acc[mi][ni] = (f32x4){0.f, 0.f, 0.f, 0.f};

    const ushort* aB = ctxT + ((size_t)(b * HID + h0 + wr * 32)) * CLEN + ks * 512;
    const ushort* bB = P2T + ((size_t)(b * QLEN + wc * 64)) * CLEN + ks * 512;

    #pragma unroll 2
    for (int kk = 0; kk < 16; kk++) {
        int k = kk * 32 + g * 8;
        bf16x8 a[2], bq[4];
        #pragma unroll
        for (int mi = 0; mi < 2; mi++)
            a[mi] = *reinterpret_cast<const bf16x8*>(aB + (size_t)(mi * 16 + ln) * CLEN + k);
        #pragma unroll
        for (int ni = 0; ni < 4; ni++)
            bq[ni] = *reinterpret_cast<const bf16x8*>(bB + (size_t)(ni * 16 + ln) * CLEN + k);
        #pragma unroll
        for (int mi = 0; mi < 2; mi++)
            #pragma unroll
            for (int ni = 0; ni < 4; ni++)
                acc[mi][ni] = MFMA(a[mi], bq[ni], acc[mi][ni]);
    }
    float* dst = Tpart + (size_t)ks * (BATCH * HID * QLEN);
    #pragma unroll
    for (int mi = 0; mi < 2; mi++)
        #pragma unroll
        for (int ni = 0; ni < 4; ni++)
            #pragma unroll
            for (int r = 0; r < 4; r++) {
                int h = h0 + wr * 32 + mi * 16 + g * 4 + r;
                int q = wc * 64 + ni * 16 + ln;
                dst[((size_t)b * HID + h) * QLEN + q] = acc[mi][ni][r];
            }
}

// ====== cs_kernel: SR from psum; Tt = (Tpart0+Tpart1)*SR ======
__global__ __launch_bounds__(256) void cs_kernel(
    const float* __restrict__ psum, const float* __restrict__ Tpart,
    ushort* __restrict__ Tt)
{
    __shared__ float SR[128];
    int hc = blockIdx.x, b = blockIdx.y;
    int t = threadIdx.x;
    if (t < 128) {
        float s = 0.f;
        #pragma unroll
        for (int j = 0; j < 16; j++)
            s += psum[((size_t)b * 16 + j) * QLEN + t];
        SR[t] = 1.0f / s;
    }
    __syncthreads();
    int h = hc * 32 + (t >> 3), qs = (t & 7) * 16;
    const float* p0 = Tpart + ((size_t)b * HID + h) * QLEN + qs;
    const float* p1 = p0 + (size_t)BATCH * HID * QLEN;
    uint pk[8];
    #pragma unroll
    for (int seg = 0; seg < 4; seg++) {
        float4 xa = *reinterpret_cast<const float4*>(p0 + seg * 4);
        float4 xb = *reinterpret_cast<const float4*>(p1 + seg * 4);
        float r0 = (xa.x + xb.x) * SR[qs + seg * 4 + 0];
        float r1 = (xa.y + xb.y) * SR[qs + seg * 4 + 1];
        float r2 = (xa.z + xb.z) * SR[qs + seg * 4 + 2];
        float r3 = (xa.w + xb.w) * SR[qs + seg * 4 + 3];
        pk[seg * 2 + 0] = (uint)f2b(r0) | ((uint)f2b(r1) << 16);
        pk[seg * 2 + 1] = (uint)f2b(r2) | ((uint)f2b(r3) << 16);
    }
    ushort* dst = Tt + ((size_t)b * HID + h) * QLEN + qs;
    uint4 w0; w0.x = pk[0]; w0.y = pk[1]; w0.z = pk[2]; w0.w = pk[3];
    uint4 w1; w1.x = pk[4]; w1.y = pk[5]; w1.z = pk[6]; w1.w = pk[7];
    *reinterpret_cast<uint4*>(dst)     = w0;
    *reinterpret_cast<uint4*>(dst + 8) = w1;
}

// ====== ab_out: 32c x 128h blocks (2048 total, 8/CU) ======
__global__ __launch_bounds__(256) void ab_out_kernel(
    const ushort* __restrict__ S, const ushort* __restrict__ qT,
    const ushort* __restrict__ Tt, const ushort* __restrict__ ctxB,
    float* __restrict__ out)
{
    __shared__ float ldsA[32][68];
    __shared__ float ldsB[32][68];
    int x = blockIdx.x, b = blockIdx.y;
    int c0 = (x & 31) * 32, h0 = (x >> 5) * 128;
    int t = threadIdx.x;
    int wv = t >> 6, L = t & 63, g = L >> 4, ln = L & 15;

    f32x4 accA[2][2], accB[2][2];
    #pragma unroll
    for (int mi = 0; mi < 2; mi++)
        #pragma unroll
        for (int ni = 0; ni < 2; ni++) {
            accA[mi][ni] = (f32x4){0.f, 0.f, 0.f, 0.f};
            accB[mi][ni] = (f32x4){0.f, 0.f, 0.f, 0.f};
        }

    const ushort* Srow = S + ((size_t)(b * CLEN + c0)) * QLEN;
    const ushort* qTb  = qT + ((size_t)(b * HID + h0 + wv * 32)) * QLEN;
    const ushort* TtB  = Tt + ((size_t)(b * HID + h0 + wv * 32)) * QLEN;

    #pragma unroll
    for (int kk = 0; kk < 4; kk++) {
        int k = kk * 32 + g * 8;
        bf16x8 sa[2], pa[2], bq[2], bt[2];
        #pragma unroll
        for (int mi = 0; mi < 2; mi++) {
            sa[mi] = *reinterpret_cast<const bf16x8*>(Srow + (size_t)(mi * 16 + ln) * QLEN + k);
            bf16x8 pv;
            #pragma unroll
            for (int i = 0; i < 8; i++)
                pv[i] = (short)f2b(__expf(b2f((ushort)sa[mi][i])));
            pa[mi] = pv;
        }
        #pragma unroll
        for (int ni = 0; ni < 2; ni++) {
            bq[ni] = *reinterpret_cast<const bf16x8*>(qTb + (size_t)(ni * 16 + ln) * QLEN + k);
            bt[ni] = *reinterpret_cast<const bf16x8*>(TtB + (size_t)(ni * 16 + ln) * QLEN + k);
        }
        #pragma unroll
        for (int mi = 0; mi < 2; mi++)
            #pragma unroll
            for (int ni = 0; ni < 2; ni++) {
                accA[mi][ni] = MFMA(sa[mi], bq[ni], accA[mi][ni]);
                accB[mi][ni] = MFMA(pa[mi], bt[ni], accB[mi][ni]);
            }
    }

    #pragma unroll
    for (int hh = 0; hh < 2; hh++) {
        if ((wv >> 1) == hh) {
            int hc = wv & 1;
            #pragma unroll
            for (int mi = 0; mi < 2; mi++)
                #pragma unroll
                for (int ni = 0; ni < 2; ni++)
                    #pragma unroll
                    for (int r = 0; r < 4; r++) {
                        ldsA[mi * 16 + g * 4 + r][hc * 32 + ni * 16 + ln] = accA[mi][ni][r];
                        ldsB[mi * 16 + g * 4 + r][hc * 32 + ni * 16 + ln] = accB[mi][ni][r];
                    }
        }
        __syncthreads();
        {
            int h8 = t & 7, c = t >> 3;
            bf16x8 cb = *reinterpret_cast<const bf16x8*>(
                ctxB + ((size_t)(b * CLEN + c0 + c)) * HID + h0 + hh * 64 + h8 * 8);
            float cf[8];
            #pragma unroll
            for (int j = 0; j < 8; j++) cf[j] = b2f((ushort)cb[j]);
            float4 a0 = *reinterpret_cast<const float4*>(&ldsA[c][h8 * 8]);
            float4 a1 = *reinterpret_cast<const float4*>(&ldsA[c][h8 * 8 + 4]);
            float4 b0 = *reinterpret_cast<const float4*>(&ldsB[c][h8 * 8]);
            float4 b1 = *reinterpret_cast<const float4*>(&ldsB[c][h8 * 8 + 4]);
            size_t o = ((size_t)(b * CLEN + c0 + c)) * 1024 + h0 + hh * 64 + h8 * 8;
            *reinterpret_cast<float4*>(&out[o])     = make_float4(cf[0], cf[1], cf[2], cf[3]);
            *reinterpret_cast<float4*>(&out[o + 4]) = make_float4(cf[4], cf[5], cf[6], cf[7]);
            *reinterpret_cast<float4*>(&out[o + 256]) = a0;
            *reinterpret_cast<float4*>(&out[o + 260]) = a1;
            *reinterpret_cast<float4*>(&out[o + 512]) =
                make_float4(cf[0] * a0.x, cf[1] * a0.y, cf[2] * a0.z, cf[3] * a0.w);
            *reinterpret_cast<float4*>(&out[o + 516]) =
                make_float4(cf[4] * a1.x, cf[5] * a1.y, cf[6] * a1.z, cf[7] * a1.w);
            *reinterpret_cast<float4*>(&out[o + 768]) =
                make_float4(cf[0] * b0.x, cf[1] * b0.y, cf[2] * b0.z, cf[3] * b0.w);
            *reinterpret_cast<float4*>(&out[o + 772]) =
                make_float4(cf[4] * b1.x, cf[5] * b1.y, cf[6] * b1.z, cf[7] * b1.w);
        }
        __syncthreads();
    }
}

extern "C" void kernel_launch(void* const* d_in, const int* in_sizes, int n_in,
                              void* d_out, int out_size, void* d_ws, size_t ws_size,
                              hipStream_t stream)
{
    (void)in_sizes; (void)n_in; (void)out_size; (void)ws_size;
    const float* context   = (const float*)d_in[0];
    const float* query     = (const float*)d_in[1];
    const float* c_weight  = (const float*)d_in[4];
    const float* q_weight  = (const float*)d_in[5];
    const float* cq_weight = (const float*)d_in[6];
    const float* bias      = (const float*)d_in[7];
    float* out = (float*)d_out;
    char* wsb  = (char*)d_ws;

    ushort* ctxB = (ushort*)(wsb);                       // 16,777,216 B
    ushort* ctxT = (ushort*)(wsb + 16777216);            // 16,777,216 B
    ushort* qmB  = (ushort*)(wsb + 33554432);            //  2,097,152 B
    ushort* qT   = (ushort*)(wsb + 35651584);            //  2,097,152 B
    ushort* S    = (ushort*)(wsb + 37748736);            //  8,388,608 B
    ushort* P2T  = (ushort*)(wsb + 46137344);            //  8,388,608 B
    ushort* Tt   = (ushort*)(wsb + 54525952);            //  2,097,152 B
    float*  Tpart = (float*)(wsb + 56623104);            //  8,388,608 B (2 slices)
    float*  cdot  = (float*)(wsb + 65011712);            //    131,072 B
    float*  qdot  = cdot + 32768;                        //     16,384 B
    float*  psum  = qdot + 4096;                         //    262,144 B

    prep_kernel<<<576, 256, 0, stream>>>(context, query, c_weight, q_weight,
                                         cq_weight, ctxB, ctxT, qmB, qT,
                                         cdot, qdot);
    s_kernel<<<dim3(16, 32), 256, 0, stream>>>(ctxB, qmB, cdot, qdot, bias,
                                               S, P2T, psum);
    t_kernel<<<dim3(8, 32), 256, 0, stream>>>(ctxT, P2T, Tpart);
    cs_kernel<<<dim3(8, 32), 256, 0, stream>>>(psum, Tpart, Tt);
    ab_out_kernel<<<dim3(64, 32), 256, 0, stream>>>(S, qT, Tt, ctxB, out);
}